// Round 6
// baseline (333.596 us; speedup 1.0000x reference)
//
#include <hip/hip_runtime.h>

// QuantumMotivicTile — B=4, S=2048, H=16, hd=64, D=1024, fp32 I/O.
// final = softmax(q k^T / 8) @ v'' + ecv
//   Aq = QS·Wq·Wi (QS = 0.125·log2e → scores in log2 domain, exp2 softmax),
//   Ak = Wk·Wi (bias cancels in softmax), Av = M·Wv·Wi, M = Wmi·Wm·Wci·Wc,
//   ecv = M·(Wv·bi+bv) + cvec.
// R11: triangulation round. R8/R9/R10 fused variants all NaN'd despite
// content-identical math vs the R7-verified composition. This round ships the
// ORIGINAL in-loop-projection kernel qmt_attn_fb TEXTUALLY UNMODIFIED from the
// shipped listings (ps_s Q/P path with pk2r, serial max chain, always-rescale,
// single buffer, 2 barriers, 2-D grid (16,64), no swizzle/setprio/pack2/
// defer-max), as the sole attention kernel. Combine is the R6/R7-verified
// 3-role-block version, byte-identical. ws = 25KB (weights only) — tests the
// ledger-gap hypothesis (harness reset() restore dispatches scale with ws
// size; 33MB ws ≈ the invariant ~124µs gap).

#define SEQ 2048
#define DM  1024
#define HD  64
#define QS  0.180336880111120429f  // 0.125 * log2(e)

typedef short bf16x8 __attribute__((ext_vector_type(8)));
typedef float f32x16 __attribute__((ext_vector_type(16)));

#define MFMA32 __builtin_amdgcn_mfma_f32_32x32x16_bf16

#if defined(__has_builtin)
#if __has_builtin(__builtin_amdgcn_exp2f)
#define EXP2(x) __builtin_amdgcn_exp2f(x)
#endif
#endif
#ifndef EXP2
#define EXP2(x) exp2f(x)
#endif

// ws layout:
//   float [0..63] bq' (×QS), [64..127] ecv
//   ushort base wsu = (ushort*)(ws+128):
//     [0..4095]      Aq (×QS) row-major [dout][din]
//     [4096..8191]   Ak row-major
//     [8192..12287]  Av row-major
#define WS_NEED ((size_t)512 + 2ull * 12288)

__device__ __forceinline__ unsigned short f2bf(float f) {
    unsigned int v = __float_as_uint(f);
    unsigned int r = v + 0x7FFFu + ((v >> 16) & 1u);
    return (unsigned short)(r >> 16);
}
__device__ __forceinline__ unsigned int pk2r(float a, float b) {
    return __builtin_amdgcn_perm(__float_as_uint(b) + 0x8000u,
                                 __float_as_uint(a) + 0x8000u, 0x07060302u);
}
__device__ __forceinline__ unsigned int pk2t(float a, float b) {
    return __builtin_amdgcn_perm(__float_as_uint(b), __float_as_uint(a), 0x07060302u);
}
__device__ __forceinline__ f32x16 z16() {
    f32x16 v;
    #pragma unroll
    for (int i = 0; i < 16; i++) v[i] = 0.f;
    return v;
}

// acc[0..16) = (wrow · L)[i0..i0+16); wrow/L in LDS, row stride 68 floats
__device__ __forceinline__ void mm16L(const float* __restrict__ wrow,
                                      const float* __restrict__ L, int i0,
                                      float* __restrict__ acc) {
    #pragma unroll
    for (int ii = 0; ii < 16; ii++) acc[ii] = 0.f;
    for (int t = 0; t < 64; t += 4) {
        float4 w4 = *(const float4*)(wrow + t);
        #pragma unroll
        for (int d = 0; d < 4; d++) {
            float wv = (d == 0) ? w4.x : (d == 1) ? w4.y : (d == 2) ? w4.z : w4.w;
            const float* lr = L + (t + d) * 68 + i0;
            float4 a = *(const float4*)lr;
            float4 b = *(const float4*)(lr + 4);
            float4 c = *(const float4*)(lr + 8);
            float4 e = *(const float4*)(lr + 12);
            acc[0] += wv * a.x;  acc[1] += wv * a.y;  acc[2]  += wv * a.z;  acc[3]  += wv * a.w;
            acc[4] += wv * b.x;  acc[5] += wv * b.y;  acc[6]  += wv * b.z;  acc[7]  += wv * b.w;
            acc[8] += wv * c.x;  acc[9] += wv * c.y;  acc[10] += wv * c.z;  acc[11] += wv * c.w;
            acc[12] += wv * e.x; acc[13] += wv * e.y; acc[14] += wv * e.z;  acc[15] += wv * e.w;
        }
    }
}

// ---------------- weight folding (3 role blocks, 256 threads, all-LDS) ----------------
// role 0: Aq + bq'   role 1: Ak   role 2: Wvi -> M -> Av + ecv (chain)
// BYTE-IDENTICAL to the R6/R7 verified version.
__global__ __launch_bounds__(256)
void qmt_combine(const float* __restrict__ Wi,  const float* __restrict__ bi,
                 const float* __restrict__ Wq,  const float* __restrict__ bq,
                 const float* __restrict__ Wk,  const float* __restrict__ bk,
                 const float* __restrict__ Wv,  const float* __restrict__ bv,
                 const float* __restrict__ Wc,  const float* __restrict__ bc,
                 const float* __restrict__ Wci, const float* __restrict__ bci,
                 const float* __restrict__ Wm,  const float* __restrict__ bm,
                 const float* __restrict__ Wmi, const float* __restrict__ bmi,
                 float* __restrict__ ws) {
    const int tid = threadIdx.x;
    const int o = tid & 63;
    const int i0 = (tid >> 6) * 16;
    const bool lead = (tid < 64);
    const int role = blockIdx.x;

    __shared__ float Wa_s[64 * 68];
    __shared__ float Wi_s[64 * 68];
    __shared__ float Wvi_s[64 * 68];
    __shared__ float M_s[64 * 68];
    __shared__ float Wc_s[512];
    __shared__ float Wci_s[512];
    __shared__ float Wm_s[256];
    __shared__ float Wmi_s[256];
    __shared__ float bi_s[64], bvi_s[64], c1[64], c2[4];
    __shared__ float U1[32], U2[256];

    unsigned short* wsu = (unsigned short*)(ws + 128);
    const float* Wa = (role == 0) ? Wq : (role == 1) ? Wk : Wv;

    for (int i4 = tid; i4 < 1024; i4 += 256) {
        int r = i4 >> 4, c = (i4 & 15) * 4;
        *(float4*)&Wi_s[r * 68 + c] = *(const float4*)(Wi + i4 * 4);
        *(float4*)&Wa_s[r * 68 + c] = *(const float4*)(Wa + i4 * 4);
    }
    if (role == 2) {
        if (tid < 128) {
            *(float4*)&Wc_s[tid * 4]  = *(const float4*)(Wc + tid * 4);
            *(float4*)&Wci_s[tid * 4] = *(const float4*)(Wci + tid * 4);
        } else if (tid < 192) {
            int t = tid - 128;
            *(float4*)&Wm_s[t * 4]  = *(const float4*)(Wm + t * 4);
            *(float4*)&Wmi_s[t * 4] = *(const float4*)(Wmi + t * 4);
        }
    }
    if (lead) bi_s[o] = bi[o];
    __syncthreads();  // (1)

    float acc[16];
    if (role == 0) {
        mm16L(Wa_s + o * 68, Wi_s, i0, acc);
        #pragma unroll
        for (int ii = 0; ii < 16; ii++) wsu[o * 64 + i0 + ii] = f2bf(acc[ii] * QS);
        if (lead) {
            float s = bq[o];
            for (int t = 0; t < 64; t++) s += Wa_s[o * 68 + t] * bi_s[t];
            ws[o] = s * QS;
        }
        return;
    }
    if (role == 1) {
        mm16L(Wa_s + o * 68, Wi_s, i0, acc);
        #pragma unroll
        for (int ii = 0; ii < 16; ii++) wsu[4096 + o * 64 + i0 + ii] = f2bf(acc[ii]);
        return;
    }
    mm16L(Wa_s + o * 68, Wi_s, i0, acc);
    #pragma unroll
    for (int ii = 0; ii < 16; ii++) Wvi_s[o * 68 + i0 + ii] = acc[ii];
    if (lead) {
        float s = bv[o];
        for (int t = 0; t < 64; t++) s += Wa_s[o * 68 + t] * bi_s[t];
        bvi_s[o] = s;
    }
    if (tid < 32) {
        int a = tid >> 3, c = tid & 7;
        float s = 0.f;
        for (int t = 0; t < 64; t++) s += Wm_s[a * 64 + t] * Wci_s[t * 8 + c];
        U1[a * 8 + c] = s;
    }
    __syncthreads();  // (2)
    if (lead) {
        for (int a = 0; a < 4; a++) {
            float s = 0.f;
            for (int cc = 0; cc < 8; cc++) s += U1[a * 8 + cc] * Wc_s[cc * 64 + o];
            U2[a * 64 + o] = s;
        }
        float s = bci[o];
        for (int j = 0; j < 8; j++) s += Wci_s[o * 8 + j] * bc[j];
        c1[o] = s;
    }
    __syncthreads();  // (3)
    #pragma unroll
    for (int ii = 0; ii < 16; ii++) {
        float s = 0.f;
        for (int a = 0; a < 4; a++) s += Wmi_s[o * 4 + a] * U2[a * 64 + i0 + ii];
        M_s[o * 68 + i0 + ii] = s;
    }
    if (tid < 4) {
        float s = bm[tid];
        for (int i = 0; i < 64; i++) s += Wm_s[tid * 64 + i] * c1[i];
        c2[tid] = s;
    }
    __syncthreads();  // (4)
    mm16L(M_s + o * 68, Wvi_s, i0, acc);
    #pragma unroll
    for (int ii = 0; ii < 16; ii++) wsu[8192 + o * 64 + i0 + ii] = f2bf(acc[ii]);
    if (lead) {
        float bvv = 0.f;
        for (int t = 0; t < 64; t++) bvv += M_s[o * 68 + t] * bvi_s[t];
        float cvv = bmi[o];
        for (int a = 0; a < 4; a++) cvv += Wmi_s[o * 4 + a] * c2[a];
        ws[64 + o] = cvv + bvv;
    }
}

// ---------------- fallback attention (in-loop KV projection) ----------------
// TEXTUALLY UNMODIFIED from the shipped R5-R7 listings.
__global__ __launch_bounds__(256, 3)
void qmt_attn_fb(const float* __restrict__ x, const float* __restrict__ wsf,
                 float* __restrict__ out) {
    __shared__ __align__(16) unsigned short ps_s[128 * 72];
    __shared__ __align__(16) unsigned short ks_s[64 * 72];
    __shared__ __align__(16) unsigned short vt_s[64 * 72];
    __shared__ float als_l[128];
    __shared__ float ls_l[128];

    const int tid = threadIdx.x;
    const int w = tid >> 6;
    const int lane = tid & 63;
    const int ln = lane & 31;
    const int h = lane >> 5;
    const int b = blockIdx.y >> 4;
    const int hh = blockIdx.y & 15;
    const int qbase = blockIdx.x * 128;

    const unsigned short* wsu = (const unsigned short*)(wsf + 128);

    bf16x8 akf[4], avf[4];
    #pragma unroll
    for (int c = 0; c < 4; c++) {
        int row = (w & 1) * 32 + ln;
        int col = c * 16 + h * 8;
        akf[c] = *(const bf16x8*)(wsu + 4096 + row * 64 + col);
        avf[c] = *(const bf16x8*)(wsu + 8192 + row * 64 + col);
    }
    const float ec0 = wsf[64 + ln];
    const float ec1 = wsf[96 + ln];

    bf16x8 qf[4];
    {
        bf16x8 xq[4];
        const float* xrow = x + ((size_t)(b * SEQ + qbase + w * 32 + ln) * DM + hh * HD);
        #pragma unroll
        for (int c = 0; c < 4; c++) {
            const float* p = xrow + c * 16 + h * 8;
            float4 f0 = *(const float4*)p;
            float4 f1 = *(const float4*)(p + 4);
            union { bf16x8 v; unsigned int u[4]; } t;
            t.u[0] = pk2t(f0.x, f0.y); t.u[1] = pk2t(f0.z, f0.w);
            t.u[2] = pk2t(f1.x, f1.y); t.u[3] = pk2t(f1.z, f1.w);
            xq[c] = t.v;
        }
        #pragma unroll
        for (int m = 0; m < 2; m++) {
            f32x16 acc;
            #pragma unroll
            for (int g = 0; g < 4; g++) {
                float4 b4 = *(const float4*)&wsf[m * 32 + 8 * g + 4 * h];
                acc[4 * g + 0] = b4.x; acc[4 * g + 1] = b4.y;
                acc[4 * g + 2] = b4.z; acc[4 * g + 3] = b4.w;
            }
            #pragma unroll
            for (int c = 0; c < 4; c++) {
                bf16x8 aq = *(const bf16x8*)(wsu + (m * 32 + ln) * 64 + c * 16 + h * 8);
                acc = MFMA32(aq, xq[c], acc, 0, 0, 0);
            }
            #pragma unroll
            for (int g = 0; g < 4; g++) {
                uint2 pw;
                pw.x = pk2r(acc[4 * g + 0], acc[4 * g + 1]);
                pw.y = pk2r(acc[4 * g + 2], acc[4 * g + 3]);
                *(uint2*)&ps_s[(w * 32 + ln) * 72 + m * 32 + 8 * g + 4 * h] = pw;
            }
        }
        #pragma unroll
        for (int c = 0; c < 4; c++)
            qf[c] = *(const bf16x8*)&ps_s[(w * 32 + ln) * 72 + c * 16 + h * 8];
    }

    f32x16 o0 = z16(), o1 = z16();
    float m_i = -1e30f, l_i = 0.f;

    const int krl = (w >> 1) * 32 + ln;
    const int dt32 = (w & 1) * 32;

    for (int kt = 0; kt < SEQ / 64; kt++) {
        bf16x8 xf[4];
        const float* xr = x + ((size_t)(b * SEQ + kt * 64 + krl) * DM + hh * HD);
        #pragma unroll
        for (int c = 0; c < 4; c++) {
            const float* p = xr + c * 16 + h * 8;
            float4 f0 = *(const float4*)p;
            float4 f1 = *(const float4*)(p + 4);
            union { bf16x8 v; unsigned int u[4]; } t;
            t.u[0] = pk2t(f0.x, f0.y); t.u[1] = pk2t(f0.z, f0.w);
            t.u[2] = pk2t(f1.x, f1.y); t.u[3] = pk2t(f1.z, f1.w);
            xf[c] = t.v;
        }
        f32x16 kacc = z16(), vacc = z16();
        #pragma unroll
        for (int c = 0; c < 4; c++) kacc = MFMA32(akf[c], xf[c], kacc, 0, 0, 0);
        #pragma unroll
        for (int c = 0; c < 4; c++) vacc = MFMA32(xf[c], avf[c], vacc, 0, 0, 0);
        #pragma unroll
        for (int g = 0; g < 4; g++) {
            uint2 pk_, pv_;
            pk_.x = pk2r(kacc[4 * g + 0], kacc[4 * g + 1]);
            pk_.y = pk2r(kacc[4 * g + 2], kacc[4 * g + 3]);
            *(uint2*)&ks_s[krl * 72 + dt32 + 8 * g + 4 * h] = pk_;
            pv_.x = pk2r(vacc[4 * g + 0], vacc[4 * g + 1]);
            pv_.y = pk2r(vacc[4 * g + 2], vacc[4 * g + 3]);
            *(uint2*)&vt_s[(dt32 + ln) * 72 + (w >> 1) * 32 + 8 * g + 4 * h] = pv_;
        }
        __syncthreads();

        f32x16 st0 = z16(), st1 = z16();
        #pragma unroll
        for (int c = 0; c < 4; c++) {
            bf16x8 k0 = *(const bf16x8*)&ks_s[ln * 72 + c * 16 + h * 8];
            bf16x8 k1 = *(const bf16x8*)&ks_s[(32 + ln) * 72 + c * 16 + h * 8];
            st0 = MFMA32(k0, qf[c], st0, 0, 0, 0);
            st1 = MFMA32(k1, qf[c], st1, 0, 0, 0);
        }
        float mx = st0[0];
        #pragma unroll
        for (int i = 1; i < 16; i++) mx = fmaxf(mx, st0[i]);
        #pragma unroll
        for (int i = 0; i < 16; i++) mx = fmaxf(mx, st1[i]);
        mx = fmaxf(mx, __shfl_xor(mx, 32));
        const float mn = fmaxf(m_i, mx);
        const float al = EXP2(m_i - mn);
        float ss = 0.f;
        #pragma unroll
        for (int i = 0; i < 16; i++) { st0[i] = EXP2(st0[i] - mn); ss += st0[i]; }
        #pragma unroll
        for (int i = 0; i < 16; i++) { st1[i] = EXP2(st1[i] - mn); ss += st1[i]; }
        ss += __shfl_xor(ss, 32);
        l_i = l_i * al + ss;
        m_i = mn;
        if (lane < 32) als_l[w * 32 + lane] = al;
        #pragma unroll
        for (int g = 0; g < 4; g++) {
            uint2 p0, p1;
            p0.x = pk2r(st0[4 * g + 0], st0[4 * g + 1]);
            p0.y = pk2r(st0[4 * g + 2], st0[4 * g + 3]);
            *(uint2*)&ps_s[(w * 32 + ln) * 72 + 8 * g + 4 * h] = p0;
            p1.x = pk2r(st1[4 * g + 0], st1[4 * g + 1]);
            p1.y = pk2r(st1[4 * g + 2], st1[4 * g + 3]);
            *(uint2*)&ps_s[(w * 32 + ln) * 72 + 32 + 8 * g + 4 * h] = p1;
        }
        #pragma unroll
        for (int g = 0; g < 4; g++) {
            float4 a4 = *(const float4*)&als_l[w * 32 + 8 * g + 4 * h];
            o0[4 * g + 0] *= a4.x; o0[4 * g + 1] *= a4.y;
            o0[4 * g + 2] *= a4.z; o0[4 * g + 3] *= a4.w;
            o1[4 * g + 0] *= a4.x; o1[4 * g + 1] *= a4.y;
            o1[4 * g + 2] *= a4.z; o1[4 * g + 3] *= a4.w;
        }
        #pragma unroll
        for (int c = 0; c < 4; c++) {
            bf16x8 pf = *(const bf16x8*)&ps_s[(w * 32 + ln) * 72 + c * 16 + h * 8];
            bf16x8 v0 = *(const bf16x8*)&vt_s[ln * 72 + c * 16 + h * 8];
            bf16x8 v1 = *(const bf16x8*)&vt_s[(32 + ln) * 72 + c * 16 + h * 8];
            o0 = MFMA32(pf, v0, o0, 0, 0, 0);
            o1 = MFMA32(pf, v1, o1, 0, 0, 0);
        }
        __syncthreads();
    }

    if (lane < 32) ls_l[w * 32 + lane] = l_i;
    #pragma unroll
    for (int g = 0; g < 4; g++) {
        float4 l4 = *(const float4*)&ls_l[w * 32 + 8 * g + 4 * h];
        float4 iv = make_float4(1.f / l4.x, 1.f / l4.y, 1.f / l4.z, 1.f / l4.w);
        #pragma unroll
        for (int i = 0; i < 4; i++) {
            float ivv = (i == 0) ? iv.x : (i == 1) ? iv.y : (i == 2) ? iv.z : iv.w;
            int q = qbase + w * 32 + 8 * g + 4 * h + i;
            float* orow = out + ((size_t)(b * SEQ + q) * DM + hh * HD);
            orow[ln] = o0[4 * g + i] * ivv + ec0;
            orow[32 + ln] = o1[4 * g + i] * ivv + ec1;
        }
    }
}

extern "C" void kernel_launch(void* const* d_in, const int* in_sizes, int n_in,
                              void* d_out, int out_size, void* d_ws, size_t ws_size,
                              hipStream_t stream) {
    const float* x = (const float*)d_in[0];
    float* wsf = (float*)d_ws;
    (void)ws_size;  // needs only WS_NEED (25 KB)

    qmt_combine<<<3, 256, 0, stream>>>(
        (const float*)d_in[1],  (const float*)d_in[2],
        (const float*)d_in[3],  (const float*)d_in[4],
        (const float*)d_in[5],  (const float*)d_in[6],
        (const float*)d_in[7],  (const float*)d_in[8],
        (const float*)d_in[9],  (const float*)d_in[10],
        (const float*)d_in[11], (const float*)d_in[12],
        (const float*)d_in[13], (const float*)d_in[14],
        (const float*)d_in[15], (const float*)d_in[16],
        wsf);

    dim3 grid(SEQ / 128, 64);
    qmt_attn_fb<<<grid, 256, 0, stream>>>(x, wsf, (float*)d_out);
}

// Round 7
// 295.758 us; speedup vs baseline: 1.1279x; 1.1279x over previous
//
#include <hip/hip_runtime.h>

// QuantumMotivicTile — B=4, S=2048, H=16, hd=64, D=1024, fp32 I/O.
// final = softmax(q k^T / 8) @ v'' + ecv
//   Aq = QS·Wq·Wi (QS = 0.125·log2e → scores in log2 domain, exp2 softmax),
//   Ak = Wk·Wi (bias cancels in softmax), Av = M·Wv·Wi, M = Wmi·Wm·Wci·Wc,
//   ecv = M·(Wv·bi+bv) + cvec.
// R12: R11 (PASSED, fb 250µs / total 334µs) + exactly ONE semantic increment:
//   * x-tile register prefetch: stage x rows for tile kt in regs; per iter
//     project from regs, THEN issue loads for kt+1, then barrier — hides the
//     x-load latency that made fb latency-bound (MfmaUtil 17.5%, VALUBusy 29%).
//   * tree-max instead of serial max: pure fmaxf reassociation, bit-identical.
// Everything else byte-identical to R11 (ps_s Q/P path, pk2r, serial sum,
// always-rescale, hoisted akf/avf, 2-D grid (16,64), launch_bounds (256,3)).
// Ledger (R11): fixed harness overhead ~70µs + combine ~8µs + attn. Fused path
// floor ~190µs if attn reaches ~115. R8-R10 NaN'd with many increments at
// once; isolation discipline: one per round.

#define SEQ 2048
#define DM  1024
#define HD  64
#define QS  0.180336880111120429f  // 0.125 * log2(e)

typedef short bf16x8 __attribute__((ext_vector_type(8)));
typedef float f32x16 __attribute__((ext_vector_type(16)));

#define MFMA32 __builtin_amdgcn_mfma_f32_32x32x16_bf16

#if defined(__has_builtin)
#if __has_builtin(__builtin_amdgcn_exp2f)
#define EXP2(x) __builtin_amdgcn_exp2f(x)
#endif
#endif
#ifndef EXP2
#define EXP2(x) exp2f(x)
#endif

// ws layout:
//   float [0..63] bq' (×QS), [64..127] ecv
//   ushort base wsu = (ushort*)(ws+128):
//     [0..4095]      Aq (×QS) row-major [dout][din]
//     [4096..8191]   Ak row-major
//     [8192..12287]  Av row-major
#define WS_NEED ((size_t)512 + 2ull * 12288)

__device__ __forceinline__ unsigned short f2bf(float f) {
    unsigned int v = __float_as_uint(f);
    unsigned int r = v + 0x7FFFu + ((v >> 16) & 1u);
    return (unsigned short)(r >> 16);
}
__device__ __forceinline__ unsigned int pk2r(float a, float b) {
    return __builtin_amdgcn_perm(__float_as_uint(b) + 0x8000u,
                                 __float_as_uint(a) + 0x8000u, 0x07060302u);
}
__device__ __forceinline__ unsigned int pk2t(float a, float b) {
    return __builtin_amdgcn_perm(__float_as_uint(b), __float_as_uint(a), 0x07060302u);
}
__device__ __forceinline__ f32x16 z16() {
    f32x16 v;
    #pragma unroll
    for (int i = 0; i < 16; i++) v[i] = 0.f;
    return v;
}

// acc[0..16) = (wrow · L)[i0..i0+16); wrow/L in LDS, row stride 68 floats
__device__ __forceinline__ void mm16L(const float* __restrict__ wrow,
                                      const float* __restrict__ L, int i0,
                                      float* __restrict__ acc) {
    #pragma unroll
    for (int ii = 0; ii < 16; ii++) acc[ii] = 0.f;
    for (int t = 0; t < 64; t += 4) {
        float4 w4 = *(const float4*)(wrow + t);
        #pragma unroll
        for (int d = 0; d < 4; d++) {
            float wv = (d == 0) ? w4.x : (d == 1) ? w4.y : (d == 2) ? w4.z : w4.w;
            const float* lr = L + (t + d) * 68 + i0;
            float4 a = *(const float4*)lr;
            float4 b = *(const float4*)(lr + 4);
            float4 c = *(const float4*)(lr + 8);
            float4 e = *(const float4*)(lr + 12);
            acc[0] += wv * a.x;  acc[1] += wv * a.y;  acc[2]  += wv * a.z;  acc[3]  += wv * a.w;
            acc[4] += wv * b.x;  acc[5] += wv * b.y;  acc[6]  += wv * b.z;  acc[7]  += wv * b.w;
            acc[8] += wv * c.x;  acc[9] += wv * c.y;  acc[10] += wv * c.z;  acc[11] += wv * c.w;
            acc[12] += wv * e.x; acc[13] += wv * e.y; acc[14] += wv * e.z;  acc[15] += wv * e.w;
        }
    }
}

// ---------------- weight folding (3 role blocks, 256 threads, all-LDS) ----------------
// role 0: Aq + bq'   role 1: Ak   role 2: Wvi -> M -> Av + ecv (chain)
// BYTE-IDENTICAL to the R6/R7/R11 verified version.
__global__ __launch_bounds__(256)
void qmt_combine(const float* __restrict__ Wi,  const float* __restrict__ bi,
                 const float* __restrict__ Wq,  const float* __restrict__ bq,
                 const float* __restrict__ Wk,  const float* __restrict__ bk,
                 const float* __restrict__ Wv,  const float* __restrict__ bv,
                 const float* __restrict__ Wc,  const float* __restrict__ bc,
                 const float* __restrict__ Wci, const float* __restrict__ bci,
                 const float* __restrict__ Wm,  const float* __restrict__ bm,
                 const float* __restrict__ Wmi, const float* __restrict__ bmi,
                 float* __restrict__ ws) {
    const int tid = threadIdx.x;
    const int o = tid & 63;
    const int i0 = (tid >> 6) * 16;
    const bool lead = (tid < 64);
    const int role = blockIdx.x;

    __shared__ float Wa_s[64 * 68];
    __shared__ float Wi_s[64 * 68];
    __shared__ float Wvi_s[64 * 68];
    __shared__ float M_s[64 * 68];
    __shared__ float Wc_s[512];
    __shared__ float Wci_s[512];
    __shared__ float Wm_s[256];
    __shared__ float Wmi_s[256];
    __shared__ float bi_s[64], bvi_s[64], c1[64], c2[4];
    __shared__ float U1[32], U2[256];

    unsigned short* wsu = (unsigned short*)(ws + 128);
    const float* Wa = (role == 0) ? Wq : (role == 1) ? Wk : Wv;

    for (int i4 = tid; i4 < 1024; i4 += 256) {
        int r = i4 >> 4, c = (i4 & 15) * 4;
        *(float4*)&Wi_s[r * 68 + c] = *(const float4*)(Wi + i4 * 4);
        *(float4*)&Wa_s[r * 68 + c] = *(const float4*)(Wa + i4 * 4);
    }
    if (role == 2) {
        if (tid < 128) {
            *(float4*)&Wc_s[tid * 4]  = *(const float4*)(Wc + tid * 4);
            *(float4*)&Wci_s[tid * 4] = *(const float4*)(Wci + tid * 4);
        } else if (tid < 192) {
            int t = tid - 128;
            *(float4*)&Wm_s[t * 4]  = *(const float4*)(Wm + t * 4);
            *(float4*)&Wmi_s[t * 4] = *(const float4*)(Wmi + t * 4);
        }
    }
    if (lead) bi_s[o] = bi[o];
    __syncthreads();  // (1)

    float acc[16];
    if (role == 0) {
        mm16L(Wa_s + o * 68, Wi_s, i0, acc);
        #pragma unroll
        for (int ii = 0; ii < 16; ii++) wsu[o * 64 + i0 + ii] = f2bf(acc[ii] * QS);
        if (lead) {
            float s = bq[o];
            for (int t = 0; t < 64; t++) s += Wa_s[o * 68 + t] * bi_s[t];
            ws[o] = s * QS;
        }
        return;
    }
    if (role == 1) {
        mm16L(Wa_s + o * 68, Wi_s, i0, acc);
        #pragma unroll
        for (int ii = 0; ii < 16; ii++) wsu[4096 + o * 64 + i0 + ii] = f2bf(acc[ii]);
        return;
    }
    mm16L(Wa_s + o * 68, Wi_s, i0, acc);
    #pragma unroll
    for (int ii = 0; ii < 16; ii++) Wvi_s[o * 68 + i0 + ii] = acc[ii];
    if (lead) {
        float s = bv[o];
        for (int t = 0; t < 64; t++) s += Wa_s[o * 68 + t] * bi_s[t];
        bvi_s[o] = s;
    }
    if (tid < 32) {
        int a = tid >> 3, c = tid & 7;
        float s = 0.f;
        for (int t = 0; t < 64; t++) s += Wm_s[a * 64 + t] * Wci_s[t * 8 + c];
        U1[a * 8 + c] = s;
    }
    __syncthreads();  // (2)
    if (lead) {
        for (int a = 0; a < 4; a++) {
            float s = 0.f;
            for (int cc = 0; cc < 8; cc++) s += U1[a * 8 + cc] * Wc_s[cc * 64 + o];
            U2[a * 64 + o] = s;
        }
        float s = bci[o];
        for (int j = 0; j < 8; j++) s += Wci_s[o * 8 + j] * bc[j];
        c1[o] = s;
    }
    __syncthreads();  // (3)
    #pragma unroll
    for (int ii = 0; ii < 16; ii++) {
        float s = 0.f;
        for (int a = 0; a < 4; a++) s += Wmi_s[o * 4 + a] * U2[a * 64 + i0 + ii];
        M_s[o * 68 + i0 + ii] = s;
    }
    if (tid < 4) {
        float s = bm[tid];
        for (int i = 0; i < 64; i++) s += Wm_s[tid * 64 + i] * c1[i];
        c2[tid] = s;
    }
    __syncthreads();  // (4)
    mm16L(M_s + o * 68, Wvi_s, i0, acc);
    #pragma unroll
    for (int ii = 0; ii < 16; ii++) wsu[8192 + o * 64 + i0 + ii] = f2bf(acc[ii]);
    if (lead) {
        float bvv = 0.f;
        for (int t = 0; t < 64; t++) bvv += M_s[o * 68 + t] * bvi_s[t];
        float cvv = bmi[o];
        for (int a = 0; a < 4; a++) cvv += Wmi_s[o * 4 + a] * c2[a];
        ws[64 + o] = cvv + bvv;
    }
}

// ---------------- fallback attention (in-loop KV projection) + x prefetch ----------------
// R11-verified text; sole semantic change: x rows staged in registers one tile
// ahead (loads issue after projection, latency hides under barrier+compute).
// Tree-max replaces serial max (bit-identical fmaxf reassociation).
__global__ __launch_bounds__(256, 3)
void qmt_attn_fb(const float* __restrict__ x, const float* __restrict__ wsf,
                 float* __restrict__ out) {
    __shared__ __align__(16) unsigned short ps_s[128 * 72];
    __shared__ __align__(16) unsigned short ks_s[64 * 72];
    __shared__ __align__(16) unsigned short vt_s[64 * 72];
    __shared__ float als_l[128];
    __shared__ float ls_l[128];

    const int tid = threadIdx.x;
    const int w = tid >> 6;
    const int lane = tid & 63;
    const int ln = lane & 31;
    const int h = lane >> 5;
    const int b = blockIdx.y >> 4;
    const int hh = blockIdx.y & 15;
    const int qbase = blockIdx.x * 128;

    const unsigned short* wsu = (const unsigned short*)(wsf + 128);

    bf16x8 akf[4], avf[4];
    #pragma unroll
    for (int c = 0; c < 4; c++) {
        int row = (w & 1) * 32 + ln;
        int col = c * 16 + h * 8;
        akf[c] = *(const bf16x8*)(wsu + 4096 + row * 64 + col);
        avf[c] = *(const bf16x8*)(wsu + 8192 + row * 64 + col);
    }
    const float ec0 = wsf[64 + ln];
    const float ec1 = wsf[96 + ln];

    const int krl = (w >> 1) * 32 + ln;
    const int dt32 = (w & 1) * 32;

    // ---- prefetch x rows for tile 0 (in flight under Q projection) ----
    float4 xl[8];
    {
        const float* xr = x + ((size_t)(b * SEQ + 0 * 64 + krl) * DM + hh * HD);
        #pragma unroll
        for (int c = 0; c < 4; c++) {
            const float* p = xr + c * 16 + h * 8;
            xl[2 * c]     = *(const float4*)p;
            xl[2 * c + 1] = *(const float4*)(p + 4);
        }
    }

    bf16x8 qf[4];
    {
        bf16x8 xq[4];
        const float* xrow = x + ((size_t)(b * SEQ + qbase + w * 32 + ln) * DM + hh * HD);
        #pragma unroll
        for (int c = 0; c < 4; c++) {
            const float* p = xrow + c * 16 + h * 8;
            float4 f0 = *(const float4*)p;
            float4 f1 = *(const float4*)(p + 4);
            union { bf16x8 v; unsigned int u[4]; } t;
            t.u[0] = pk2t(f0.x, f0.y); t.u[1] = pk2t(f0.z, f0.w);
            t.u[2] = pk2t(f1.x, f1.y); t.u[3] = pk2t(f1.z, f1.w);
            xq[c] = t.v;
        }
        #pragma unroll
        for (int m = 0; m < 2; m++) {
            f32x16 acc;
            #pragma unroll
            for (int g = 0; g < 4; g++) {
                float4 b4 = *(const float4*)&wsf[m * 32 + 8 * g + 4 * h];
                acc[4 * g + 0] = b4.x; acc[4 * g + 1] = b4.y;
                acc[4 * g + 2] = b4.z; acc[4 * g + 3] = b4.w;
            }
            #pragma unroll
            for (int c = 0; c < 4; c++) {
                bf16x8 aq = *(const bf16x8*)(wsu + (m * 32 + ln) * 64 + c * 16 + h * 8);
                acc = MFMA32(aq, xq[c], acc, 0, 0, 0);
            }
            #pragma unroll
            for (int g = 0; g < 4; g++) {
                uint2 pw;
                pw.x = pk2r(acc[4 * g + 0], acc[4 * g + 1]);
                pw.y = pk2r(acc[4 * g + 2], acc[4 * g + 3]);
                *(uint2*)&ps_s[(w * 32 + ln) * 72 + m * 32 + 8 * g + 4 * h] = pw;
            }
        }
        #pragma unroll
        for (int c = 0; c < 4; c++)
            qf[c] = *(const bf16x8*)&ps_s[(w * 32 + ln) * 72 + c * 16 + h * 8];
    }

    f32x16 o0 = z16(), o1 = z16();
    float m_i = -1e30f, l_i = 0.f;

    for (int kt = 0; kt < SEQ / 64; kt++) {
        // ---- project K/V tile kt from staged registers (R11 transforms) ----
        bf16x8 xf[4];
        #pragma unroll
        for (int c = 0; c < 4; c++) {
            union { bf16x8 v; unsigned int u[4]; } t;
            t.u[0] = pk2t(xl[2 * c].x, xl[2 * c].y);
            t.u[1] = pk2t(xl[2 * c].z, xl[2 * c].w);
            t.u[2] = pk2t(xl[2 * c + 1].x, xl[2 * c + 1].y);
            t.u[3] = pk2t(xl[2 * c + 1].z, xl[2 * c + 1].w);
            xf[c] = t.v;
        }
        f32x16 kacc = z16(), vacc = z16();
        #pragma unroll
        for (int c = 0; c < 4; c++) kacc = MFMA32(akf[c], xf[c], kacc, 0, 0, 0);
        #pragma unroll
        for (int c = 0; c < 4; c++) vacc = MFMA32(xf[c], avf[c], vacc, 0, 0, 0);
        #pragma unroll
        for (int g = 0; g < 4; g++) {
            uint2 pk_, pv_;
            pk_.x = pk2r(kacc[4 * g + 0], kacc[4 * g + 1]);
            pk_.y = pk2r(kacc[4 * g + 2], kacc[4 * g + 3]);
            *(uint2*)&ks_s[krl * 72 + dt32 + 8 * g + 4 * h] = pk_;
            pv_.x = pk2r(vacc[4 * g + 0], vacc[4 * g + 1]);
            pv_.y = pk2r(vacc[4 * g + 2], vacc[4 * g + 3]);
            *(uint2*)&vt_s[(dt32 + ln) * 72 + (w >> 1) * 32 + 8 * g + 4 * h] = pv_;
        }
        // ---- issue x loads for tile kt+1 (hide latency under barrier+compute) ----
        if (kt + 1 < SEQ / 64) {
            const float* xr = x + ((size_t)(b * SEQ + (kt + 1) * 64 + krl) * DM + hh * HD);
            #pragma unroll
            for (int c = 0; c < 4; c++) {
                const float* p = xr + c * 16 + h * 8;
                xl[2 * c]     = *(const float4*)p;
                xl[2 * c + 1] = *(const float4*)(p + 4);
            }
        }
        __syncthreads();

        f32x16 st0 = z16(), st1 = z16();
        #pragma unroll
        for (int c = 0; c < 4; c++) {
            bf16x8 k0 = *(const bf16x8*)&ks_s[ln * 72 + c * 16 + h * 8];
            bf16x8 k1 = *(const bf16x8*)&ks_s[(32 + ln) * 72 + c * 16 + h * 8];
            st0 = MFMA32(k0, qf[c], st0, 0, 0, 0);
            st1 = MFMA32(k1, qf[c], st1, 0, 0, 0);
        }
        // tile max — tree (bit-identical reassociation of fmaxf)
        float tm[8];
        #pragma unroll
        for (int i = 0; i < 8; i++)
            tm[i] = fmaxf(fmaxf(st0[i], st0[i + 8]), fmaxf(st1[i], st1[i + 8]));
        #pragma unroll
        for (int i = 0; i < 4; i++) tm[i] = fmaxf(tm[i], tm[i + 4]);
        float mx = fmaxf(fmaxf(tm[0], tm[1]), fmaxf(tm[2], tm[3]));
        mx = fmaxf(mx, __shfl_xor(mx, 32));
        const float mn = fmaxf(m_i, mx);
        const float al = EXP2(m_i - mn);
        float ss = 0.f;
        #pragma unroll
        for (int i = 0; i < 16; i++) { st0[i] = EXP2(st0[i] - mn); ss += st0[i]; }
        #pragma unroll
        for (int i = 0; i < 16; i++) { st1[i] = EXP2(st1[i] - mn); ss += st1[i]; }
        ss += __shfl_xor(ss, 32);
        l_i = l_i * al + ss;
        m_i = mn;
        if (lane < 32) als_l[w * 32 + lane] = al;
        #pragma unroll
        for (int g = 0; g < 4; g++) {
            uint2 p0, p1;
            p0.x = pk2r(st0[4 * g + 0], st0[4 * g + 1]);
            p0.y = pk2r(st0[4 * g + 2], st0[4 * g + 3]);
            *(uint2*)&ps_s[(w * 32 + ln) * 72 + 8 * g + 4 * h] = p0;
            p1.x = pk2r(st1[4 * g + 0], st1[4 * g + 1]);
            p1.y = pk2r(st1[4 * g + 2], st1[4 * g + 3]);
            *(uint2*)&ps_s[(w * 32 + ln) * 72 + 32 + 8 * g + 4 * h] = p1;
        }
        #pragma unroll
        for (int g = 0; g < 4; g++) {
            float4 a4 = *(const float4*)&als_l[w * 32 + 8 * g + 4 * h];
            o0[4 * g + 0] *= a4.x; o0[4 * g + 1] *= a4.y;
            o0[4 * g + 2] *= a4.z; o0[4 * g + 3] *= a4.w;
            o1[4 * g + 0] *= a4.x; o1[4 * g + 1] *= a4.y;
            o1[4 * g + 2] *= a4.z; o1[4 * g + 3] *= a4.w;
        }
        #pragma unroll
        for (int c = 0; c < 4; c++) {
            bf16x8 pf = *(const bf16x8*)&ps_s[(w * 32 + ln) * 72 + c * 16 + h * 8];
            bf16x8 v0 = *(const bf16x8*)&vt_s[ln * 72 + c * 16 + h * 8];
            bf16x8 v1 = *(const bf16x8*)&vt_s[(32 + ln) * 72 + c * 16 + h * 8];
            o0 = MFMA32(pf, v0, o0, 0, 0, 0);
            o1 = MFMA32(pf, v1, o1, 0, 0, 0);
        }
        __syncthreads();
    }

    if (lane < 32) ls_l[w * 32 + lane] = l_i;
    #pragma unroll
    for (int g = 0; g < 4; g++) {
        float4 l4 = *(const float4*)&ls_l[w * 32 + 8 * g + 4 * h];
        float4 iv = make_float4(1.f / l4.x, 1.f / l4.y, 1.f / l4.z, 1.f / l4.w);
        #pragma unroll
        for (int i = 0; i < 4; i++) {
            float ivv = (i == 0) ? iv.x : (i == 1) ? iv.y : (i == 2) ? iv.z : iv.w;
            int q = qbase + w * 32 + 8 * g + 4 * h + i;
            float* orow = out + ((size_t)(b * SEQ + q) * DM + hh * HD);
            orow[ln] = o0[4 * g + i] * ivv + ec0;
            orow[32 + ln] = o1[4 * g + i] * ivv + ec1;
        }
    }
}

extern "C" void kernel_launch(void* const* d_in, const int* in_sizes, int n_in,
                              void* d_out, int out_size, void* d_ws, size_t ws_size,
                              hipStream_t stream) {
    const float* x = (const float*)d_in[0];
    float* wsf = (float*)d_ws;
    (void)ws_size;  // needs only WS_NEED (25 KB)

    qmt_combine<<<3, 256, 0, stream>>>(
        (const float*)d_in[1],  (const float*)d_in[2],
        (const float*)d_in[3],  (const float*)d_in[4],
        (const float*)d_in[5],  (const float*)d_in[6],
        (const float*)d_in[7],  (const float*)d_in[8],
        (const float*)d_in[9],  (const float*)d_in[10],
        (const float*)d_in[11], (const float*)d_in[12],
        (const float*)d_in[13], (const float*)d_in[14],
        (const float*)d_in[15], (const float*)d_in[16],
        wsf);

    dim3 grid(SEQ / 128, 64);
    qmt_attn_fb<<<grid, 256, 0, stream>>>(x, wsf, (float*)d_out);
}

// Round 8
// 281.861 us; speedup vs baseline: 1.1835x; 1.0493x over previous
//
#include <hip/hip_runtime.h>

// QuantumMotivicTile — B=4, S=2048, H=16, hd=64, D=1024, fp32 I/O.
// final = softmax(q k^T / 8) @ v'' + ecv
//   Aq = QS·Wq·Wi (QS = 0.125·log2e → scores in log2 domain, exp2 softmax),
//   Ak = Wk·Wi (bias cancels in softmax), Av = M·Wv·Wi, M = Wmi·Wm·Wci·Wc,
//   ecv = M·(Wv·bi+bv) + cvec.
// R13: R12 (PASSED, fb ~211µs / total 296µs) + exactly ONE increment:
//   * register P/Q via pack2 (cvt_pk+permlane32_swap, R6/R7-verified mapping):
//     drops the ps_s LDS round-trip for P (per iter: -24 VALU, -8 LDS writes,
//     -4 LDS reads, ~-4M bank-conflict cycles) and for Q (prologue).
//     ps_s deleted -> LDS 37888 -> 19456 (4 blocks/CU by LDS if VGPR<=128).
// Everything else byte-identical to R12 (x-reg prefetch, tree-max, serial sum,
// always-rescale, als_l, hoisted akf/avf, 2-D grid (16,64), bounds (256,3)).
// Isolation: if this NaNs, pack2-in-fused is the R8-R10 trigger; if it passes,
// R14 re-tries the dbuf 1-barrier schedule on this base.
// Ledger: fused total = attn + ~85µs (fixed harness + combine). Beat 228 banked
// iff attn < ~143.

#define SEQ 2048
#define DM  1024
#define HD  64
#define QS  0.180336880111120429f  // 0.125 * log2(e)

typedef short bf16x8 __attribute__((ext_vector_type(8)));
typedef float f32x16 __attribute__((ext_vector_type(16)));

#define MFMA32 __builtin_amdgcn_mfma_f32_32x32x16_bf16

#if defined(__has_builtin)
#if __has_builtin(__builtin_amdgcn_exp2f)
#define EXP2(x) __builtin_amdgcn_exp2f(x)
#endif
#endif
#ifndef EXP2
#define EXP2(x) exp2f(x)
#endif

// ws layout:
//   float [0..63] bq' (×QS), [64..127] ecv
//   ushort base wsu = (ushort*)(ws+128):
//     [0..4095]      Aq (×QS) row-major [dout][din]
//     [4096..8191]   Ak row-major
//     [8192..12287]  Av row-major
#define WS_NEED ((size_t)512 + 2ull * 12288)

__device__ __forceinline__ unsigned short f2bf(float f) {
    unsigned int v = __float_as_uint(f);
    unsigned int r = v + 0x7FFFu + ((v >> 16) & 1u);
    return (unsigned short)(r >> 16);
}
__device__ __forceinline__ unsigned int pk2r(float a, float b) {
    return __builtin_amdgcn_perm(__float_as_uint(b) + 0x8000u,
                                 __float_as_uint(a) + 0x8000u, 0x07060302u);
}
__device__ __forceinline__ unsigned int pk2t(float a, float b) {
    return __builtin_amdgcn_perm(__float_as_uint(b), __float_as_uint(a), 0x07060302u);
}
// {lo: bf16(a), hi: bf16(b)} — RNE, 1 VALU op
__device__ __forceinline__ unsigned int cvtpk(float a, float b) {
    unsigned int r;
    asm("v_cvt_pk_bf16_f32 %0, %1, %2" : "=v"(r) : "v"(a), "v"(b));
    return r;
}
// a' = {a.lanes0-31, b.lanes0-31}; b' = {a.lanes32-63, b.lanes32-63}
__device__ __forceinline__ void swap32(unsigned int& a, unsigned int& b) {
    asm("v_permlane32_swap_b32 %0, %1" : "+v"(a), "+v"(b));
}
__device__ __forceinline__ f32x16 z16() {
    f32x16 v;
    #pragma unroll
    for (int i = 0; i < 16; i++) v[i] = 0.f;
    return v;
}

// 32x32 MFMA C-block -> two A/B-operand bf16 fragments (rows 0..15 / 16..31).
// Verified mapping (R6/R7 hardware-passed): for lane (ln,h), after the swaps
// fA = rows h*8..h*8+7 of chunk 0..15, fB = same of rows 16..31 — identical to
// the ps_s stride-72 round-trip this replaces.
__device__ __forceinline__ void pack2(const f32x16 s, bf16x8& fA, bf16x8& fB) {
    union { bf16x8 v; unsigned int u[4]; } a, b;
    a.u[0] = cvtpk(s[0], s[1]);   a.u[1] = cvtpk(s[2], s[3]);
    a.u[2] = cvtpk(s[4], s[5]);   a.u[3] = cvtpk(s[6], s[7]);
    b.u[0] = cvtpk(s[8], s[9]);   b.u[1] = cvtpk(s[10], s[11]);
    b.u[2] = cvtpk(s[12], s[13]); b.u[3] = cvtpk(s[14], s[15]);
    swap32(a.u[0], a.u[2]); swap32(a.u[1], a.u[3]);
    swap32(b.u[0], b.u[2]); swap32(b.u[1], b.u[3]);
    fA = a.v; fB = b.v;
}

// acc[0..16) = (wrow · L)[i0..i0+16); wrow/L in LDS, row stride 68 floats
__device__ __forceinline__ void mm16L(const float* __restrict__ wrow,
                                      const float* __restrict__ L, int i0,
                                      float* __restrict__ acc) {
    #pragma unroll
    for (int ii = 0; ii < 16; ii++) acc[ii] = 0.f;
    for (int t = 0; t < 64; t += 4) {
        float4 w4 = *(const float4*)(wrow + t);
        #pragma unroll
        for (int d = 0; d < 4; d++) {
            float wv = (d == 0) ? w4.x : (d == 1) ? w4.y : (d == 2) ? w4.z : w4.w;
            const float* lr = L + (t + d) * 68 + i0;
            float4 a = *(const float4*)lr;
            float4 b = *(const float4*)(lr + 4);
            float4 c = *(const float4*)(lr + 8);
            float4 e = *(const float4*)(lr + 12);
            acc[0] += wv * a.x;  acc[1] += wv * a.y;  acc[2]  += wv * a.z;  acc[3]  += wv * a.w;
            acc[4] += wv * b.x;  acc[5] += wv * b.y;  acc[6]  += wv * b.z;  acc[7]  += wv * b.w;
            acc[8] += wv * c.x;  acc[9] += wv * c.y;  acc[10] += wv * c.z;  acc[11] += wv * c.w;
            acc[12] += wv * e.x; acc[13] += wv * e.y; acc[14] += wv * e.z;  acc[15] += wv * e.w;
        }
    }
}

// ---------------- weight folding (3 role blocks, 256 threads, all-LDS) ----------------
// role 0: Aq + bq'   role 1: Ak   role 2: Wvi -> M -> Av + ecv (chain)
// BYTE-IDENTICAL to the R6/R7/R11/R12 verified version.
__global__ __launch_bounds__(256)
void qmt_combine(const float* __restrict__ Wi,  const float* __restrict__ bi,
                 const float* __restrict__ Wq,  const float* __restrict__ bq,
                 const float* __restrict__ Wk,  const float* __restrict__ bk,
                 const float* __restrict__ Wv,  const float* __restrict__ bv,
                 const float* __restrict__ Wc,  const float* __restrict__ bc,
                 const float* __restrict__ Wci, const float* __restrict__ bci,
                 const float* __restrict__ Wm,  const float* __restrict__ bm,
                 const float* __restrict__ Wmi, const float* __restrict__ bmi,
                 float* __restrict__ ws) {
    const int tid = threadIdx.x;
    const int o = tid & 63;
    const int i0 = (tid >> 6) * 16;
    const bool lead = (tid < 64);
    const int role = blockIdx.x;

    __shared__ float Wa_s[64 * 68];
    __shared__ float Wi_s[64 * 68];
    __shared__ float Wvi_s[64 * 68];
    __shared__ float M_s[64 * 68];
    __shared__ float Wc_s[512];
    __shared__ float Wci_s[512];
    __shared__ float Wm_s[256];
    __shared__ float Wmi_s[256];
    __shared__ float bi_s[64], bvi_s[64], c1[64], c2[4];
    __shared__ float U1[32], U2[256];

    unsigned short* wsu = (unsigned short*)(ws + 128);
    const float* Wa = (role == 0) ? Wq : (role == 1) ? Wk : Wv;

    for (int i4 = tid; i4 < 1024; i4 += 256) {
        int r = i4 >> 4, c = (i4 & 15) * 4;
        *(float4*)&Wi_s[r * 68 + c] = *(const float4*)(Wi + i4 * 4);
        *(float4*)&Wa_s[r * 68 + c] = *(const float4*)(Wa + i4 * 4);
    }
    if (role == 2) {
        if (tid < 128) {
            *(float4*)&Wc_s[tid * 4]  = *(const float4*)(Wc + tid * 4);
            *(float4*)&Wci_s[tid * 4] = *(const float4*)(Wci + tid * 4);
        } else if (tid < 192) {
            int t = tid - 128;
            *(float4*)&Wm_s[t * 4]  = *(const float4*)(Wm + t * 4);
            *(float4*)&Wmi_s[t * 4] = *(const float4*)(Wmi + t * 4);
        }
    }
    if (lead) bi_s[o] = bi[o];
    __syncthreads();  // (1)

    float acc[16];
    if (role == 0) {
        mm16L(Wa_s + o * 68, Wi_s, i0, acc);
        #pragma unroll
        for (int ii = 0; ii < 16; ii++) wsu[o * 64 + i0 + ii] = f2bf(acc[ii] * QS);
        if (lead) {
            float s = bq[o];
            for (int t = 0; t < 64; t++) s += Wa_s[o * 68 + t] * bi_s[t];
            ws[o] = s * QS;
        }
        return;
    }
    if (role == 1) {
        mm16L(Wa_s + o * 68, Wi_s, i0, acc);
        #pragma unroll
        for (int ii = 0; ii < 16; ii++) wsu[4096 + o * 64 + i0 + ii] = f2bf(acc[ii]);
        return;
    }
    mm16L(Wa_s + o * 68, Wi_s, i0, acc);
    #pragma unroll
    for (int ii = 0; ii < 16; ii++) Wvi_s[o * 68 + i0 + ii] = acc[ii];
    if (lead) {
        float s = bv[o];
        for (int t = 0; t < 64; t++) s += Wa_s[o * 68 + t] * bi_s[t];
        bvi_s[o] = s;
    }
    if (tid < 32) {
        int a = tid >> 3, c = tid & 7;
        float s = 0.f;
        for (int t = 0; t < 64; t++) s += Wm_s[a * 64 + t] * Wci_s[t * 8 + c];
        U1[a * 8 + c] = s;
    }
    __syncthreads();  // (2)
    if (lead) {
        for (int a = 0; a < 4; a++) {
            float s = 0.f;
            for (int cc = 0; cc < 8; cc++) s += U1[a * 8 + cc] * Wc_s[cc * 64 + o];
            U2[a * 64 + o] = s;
        }
        float s = bci[o];
        for (int j = 0; j < 8; j++) s += Wci_s[o * 8 + j] * bc[j];
        c1[o] = s;
    }
    __syncthreads();  // (3)
    #pragma unroll
    for (int ii = 0; ii < 16; ii++) {
        float s = 0.f;
        for (int a = 0; a < 4; a++) s += Wmi_s[o * 4 + a] * U2[a * 64 + i0 + ii];
        M_s[o * 68 + i0 + ii] = s;
    }
    if (tid < 4) {
        float s = bm[tid];
        for (int i = 0; i < 64; i++) s += Wm_s[tid * 64 + i] * c1[i];
        c2[tid] = s;
    }
    __syncthreads();  // (4)
    mm16L(M_s + o * 68, Wvi_s, i0, acc);
    #pragma unroll
    for (int ii = 0; ii < 16; ii++) wsu[8192 + o * 64 + i0 + ii] = f2bf(acc[ii]);
    if (lead) {
        float bvv = 0.f;
        for (int t = 0; t < 64; t++) bvv += M_s[o * 68 + t] * bvi_s[t];
        float cvv = bmi[o];
        for (int a = 0; a < 4; a++) cvv += Wmi_s[o * 4 + a] * c2[a];
        ws[64 + o] = cvv + bvv;
    }
}

// ---------------- fused attention (in-loop KV projection, register P/Q) ----------------
// R12-verified text; sole increment: P and Q fragments via pack2 in registers
// (ps_s deleted, LDS 37888 -> 19456).
__global__ __launch_bounds__(256, 3)
void qmt_attn_fb(const float* __restrict__ x, const float* __restrict__ wsf,
                 float* __restrict__ out) {
    __shared__ __align__(16) unsigned short ks_s[64 * 72];
    __shared__ __align__(16) unsigned short vt_s[64 * 72];
    __shared__ float als_l[128];
    __shared__ float ls_l[128];

    const int tid = threadIdx.x;
    const int w = tid >> 6;
    const int lane = tid & 63;
    const int ln = lane & 31;
    const int h = lane >> 5;
    const int b = blockIdx.y >> 4;
    const int hh = blockIdx.y & 15;
    const int qbase = blockIdx.x * 128;

    const unsigned short* wsu = (const unsigned short*)(wsf + 128);

    bf16x8 akf[4], avf[4];
    #pragma unroll
    for (int c = 0; c < 4; c++) {
        int row = (w & 1) * 32 + ln;
        int col = c * 16 + h * 8;
        akf[c] = *(const bf16x8*)(wsu + 4096 + row * 64 + col);
        avf[c] = *(const bf16x8*)(wsu + 8192 + row * 64 + col);
    }
    const float ec0 = wsf[64 + ln];
    const float ec1 = wsf[96 + ln];

    const int krl = (w >> 1) * 32 + ln;
    const int dt32 = (w & 1) * 32;

    // ---- prefetch x rows for tile 0 (in flight under Q projection) ----
    float4 xl[8];
    {
        const float* xr = x + ((size_t)(b * SEQ + 0 * 64 + krl) * DM + hh * HD);
        #pragma unroll
        for (int c = 0; c < 4; c++) {
            const float* p = xr + c * 16 + h * 8;
            xl[2 * c]     = *(const float4*)p;
            xl[2 * c + 1] = *(const float4*)(p + 4);
        }
    }

    // ---- Q projection: all in registers via pack2 (R6/R7-verified) ----
    bf16x8 qf[4];
    {
        bf16x8 xq[4];
        const float* xrow = x + ((size_t)(b * SEQ + qbase + w * 32 + ln) * DM + hh * HD);
        #pragma unroll
        for (int c = 0; c < 4; c++) {
            const float* p = xrow + c * 16 + h * 8;
            float4 f0 = *(const float4*)p;
            float4 f1 = *(const float4*)(p + 4);
            union { bf16x8 v; unsigned int u[4]; } t;
            t.u[0] = pk2t(f0.x, f0.y); t.u[1] = pk2t(f0.z, f0.w);
            t.u[2] = pk2t(f1.x, f1.y); t.u[3] = pk2t(f1.z, f1.w);
            xq[c] = t.v;
        }
        #pragma unroll
        for (int m = 0; m < 2; m++) {
            f32x16 acc;
            #pragma unroll
            for (int g = 0; g < 4; g++) {
                float4 b4 = *(const float4*)&wsf[m * 32 + 8 * g + 4 * h];
                acc[4 * g + 0] = b4.x; acc[4 * g + 1] = b4.y;
                acc[4 * g + 2] = b4.z; acc[4 * g + 3] = b4.w;
            }
            #pragma unroll
            for (int c = 0; c < 4; c++) {
                bf16x8 aq = *(const bf16x8*)(wsu + (m * 32 + ln) * 64 + c * 16 + h * 8);
                acc = MFMA32(aq, xq[c], acc, 0, 0, 0);
            }
            pack2(acc, qf[2 * m], qf[2 * m + 1]);
        }
    }

    f32x16 o0 = z16(), o1 = z16();
    float m_i = -1e30f, l_i = 0.f;

    for (int kt = 0; kt < SEQ / 64; kt++) {
        // ---- project K/V tile kt from staged registers (R11/R12 transforms) ----
        bf16x8 xf[4];
        #pragma unroll
        for (int c = 0; c < 4; c++) {
            union { bf16x8 v; unsigned int u[4]; } t;
            t.u[0] = pk2t(xl[2 * c].x, xl[2 * c].y);
            t.u[1] = pk2t(xl[2 * c].z, xl[2 * c].w);
            t.u[2] = pk2t(xl[2 * c + 1].x, xl[2 * c + 1].y);
            t.u[3] = pk2t(xl[2 * c + 1].z, xl[2 * c + 1].w);
            xf[c] = t.v;
        }
        f32x16 kacc = z16(), vacc = z16();
        #pragma unroll
        for (int c = 0; c < 4; c++) kacc = MFMA32(akf[c], xf[c], kacc, 0, 0, 0);
        #pragma unroll
        for (int c = 0; c < 4; c++) vacc = MFMA32(xf[c], avf[c], vacc, 0, 0, 0);
        #pragma unroll
        for (int g = 0; g < 4; g++) {
            uint2 pk_, pv_;
            pk_.x = pk2r(kacc[4 * g + 0], kacc[4 * g + 1]);
            pk_.y = pk2r(kacc[4 * g + 2], kacc[4 * g + 3]);
            *(uint2*)&ks_s[krl * 72 + dt32 + 8 * g + 4 * h] = pk_;
            pv_.x = pk2r(vacc[4 * g + 0], vacc[4 * g + 1]);
            pv_.y = pk2r(vacc[4 * g + 2], vacc[4 * g + 3]);
            *(uint2*)&vt_s[(dt32 + ln) * 72 + (w >> 1) * 32 + 8 * g + 4 * h] = pv_;
        }
        // ---- issue x loads for tile kt+1 (hide latency under barrier+compute) ----
        if (kt + 1 < SEQ / 64) {
            const float* xr = x + ((size_t)(b * SEQ + (kt + 1) * 64 + krl) * DM + hh * HD);
            #pragma unroll
            for (int c = 0; c < 4; c++) {
                const float* p = xr + c * 16 + h * 8;
                xl[2 * c]     = *(const float4*)p;
                xl[2 * c + 1] = *(const float4*)(p + 4);
            }
        }
        __syncthreads();

        f32x16 st0 = z16(), st1 = z16();
        #pragma unroll
        for (int c = 0; c < 4; c++) {
            bf16x8 k0 = *(const bf16x8*)&ks_s[ln * 72 + c * 16 + h * 8];
            bf16x8 k1 = *(const bf16x8*)&ks_s[(32 + ln) * 72 + c * 16 + h * 8];
            st0 = MFMA32(k0, qf[c], st0, 0, 0, 0);
            st1 = MFMA32(k1, qf[c], st1, 0, 0, 0);
        }
        // tile max — tree (bit-identical reassociation of fmaxf)
        float tm[8];
        #pragma unroll
        for (int i = 0; i < 8; i++)
            tm[i] = fmaxf(fmaxf(st0[i], st0[i + 8]), fmaxf(st1[i], st1[i + 8]));
        #pragma unroll
        for (int i = 0; i < 4; i++) tm[i] = fmaxf(tm[i], tm[i + 4]);
        float mx = fmaxf(fmaxf(tm[0], tm[1]), fmaxf(tm[2], tm[3]));
        mx = fmaxf(mx, __shfl_xor(mx, 32));
        const float mn = fmaxf(m_i, mx);
        const float al = EXP2(m_i - mn);
        float ss = 0.f;
        #pragma unroll
        for (int i = 0; i < 16; i++) { st0[i] = EXP2(st0[i] - mn); ss += st0[i]; }
        #pragma unroll
        for (int i = 0; i < 16; i++) { st1[i] = EXP2(st1[i] - mn); ss += st1[i]; }
        ss += __shfl_xor(ss, 32);
        l_i = l_i * al + ss;
        m_i = mn;
        if (lane < 32) als_l[w * 32 + lane] = al;

        // ---- P -> A-fragments in registers (replaces ps_s round-trip) ----
        bf16x8 pf[4];
        pack2(st0, pf[0], pf[1]);
        pack2(st1, pf[2], pf[3]);

        #pragma unroll
        for (int g = 0; g < 4; g++) {
            float4 a4 = *(const float4*)&als_l[w * 32 + 8 * g + 4 * h];
            o0[4 * g + 0] *= a4.x; o0[4 * g + 1] *= a4.y;
            o0[4 * g + 2] *= a4.z; o0[4 * g + 3] *= a4.w;
            o1[4 * g + 0] *= a4.x; o1[4 * g + 1] *= a4.y;
            o1[4 * g + 2] *= a4.z; o1[4 * g + 3] *= a4.w;
        }
        #pragma unroll
        for (int c = 0; c < 4; c++) {
            bf16x8 v0 = *(const bf16x8*)&vt_s[ln * 72 + c * 16 + h * 8];
            bf16x8 v1 = *(const bf16x8*)&vt_s[(32 + ln) * 72 + c * 16 + h * 8];
            o0 = MFMA32(pf[c], v0, o0, 0, 0, 0);
            o1 = MFMA32(pf[c], v1, o1, 0, 0, 0);
        }
        __syncthreads();
    }

    if (lane < 32) ls_l[w * 32 + lane] = l_i;
    #pragma unroll
    for (int g = 0; g < 4; g++) {
        float4 l4 = *(const float4*)&ls_l[w * 32 + 8 * g + 4 * h];
        float4 iv = make_float4(1.f / l4.x, 1.f / l4.y, 1.f / l4.z, 1.f / l4.w);
        #pragma unroll
        for (int i = 0; i < 4; i++) {
            float ivv = (i == 0) ? iv.x : (i == 1) ? iv.y : (i == 2) ? iv.z : iv.w;
            int q = qbase + w * 32 + 8 * g + 4 * h + i;
            float* orow = out + ((size_t)(b * SEQ + q) * DM + hh * HD);
            orow[ln] = o0[4 * g + i] * ivv + ec0;
            orow[32 + ln] = o1[4 * g + i] * ivv + ec1;
        }
    }
}

extern "C" void kernel_launch(void* const* d_in, const int* in_sizes, int n_in,
                              void* d_out, int out_size, void* d_ws, size_t ws_size,
                              hipStream_t stream) {
    const float* x = (const float*)d_in[0];
    float* wsf = (float*)d_ws;
    (void)ws_size;  // needs only WS_NEED (25 KB)

    qmt_combine<<<3, 256, 0, stream>>>(
        (const float*)d_in[1],  (const float*)d_in[2],
        (const float*)d_in[3],  (const float*)d_in[4],
        (const float*)d_in[5],  (const float*)d_in[6],
        (const float*)d_in[7],  (const float*)d_in[8],
        (const float*)d_in[9],  (const float*)d_in[10],
        (const float*)d_in[11], (const float*)d_in[12],
        (const float*)d_in[13], (const float*)d_in[14],
        (const float*)d_in[15], (const float*)d_in[16],
        wsf);

    dim3 grid(SEQ / 128, 64);
    qmt_attn_fb<<<grid, 256, 0, stream>>>(x, wsf, (float*)d_out);
}